// Round 2
// baseline (998.399 us; speedup 1.0000x reference)
//
#include <hip/hip_runtime.h>
#include <hip/hip_bf16.h>

#define B_ 4
#define S_ 2048
#define D_ 512
#define H_ 8
#define QT 32
#define KT 64

// ---------------------------------------------------------------------------
// 128x128-tile fp32 GEMM, 8x8 register blocking. C = X(8192x512) @ W(512x512)
// + bias. Epilogue writes Q/K/V (scaled) to (b,h,s,d) layout in workspace.
// ---------------------------------------------------------------------------
__global__ __launch_bounds__(256) void proj_qkv(
    const float* __restrict__ Xq, const float* __restrict__ Xv,
    const float* __restrict__ Wq, const float* __restrict__ bq,
    const float* __restrict__ Wk, const float* __restrict__ bk,
    const float* __restrict__ Wv, const float* __restrict__ bv,
    float* __restrict__ Qb, float* __restrict__ Kb, float* __restrict__ Vb)
{
    const int which = blockIdx.z;
    const float* X    = (which == 0) ? Xq : Xv;
    const float* W    = (which == 0) ? Wq : (which == 1) ? Wk : Wv;
    const float* bias = (which == 0) ? bq : (which == 1) ? bk : bv;
    float* out        = (which == 0) ? Qb : (which == 1) ? Kb : Vb;
    const float scale = (which == 0) ? 0.125f : 1.0f;   // 1/sqrt(64) folded into Q

    const int n0 = blockIdx.x * 128;
    const int m0 = blockIdx.y * 128;
    const int tid = threadIdx.x;
    const int tx = tid & 15;
    const int ty = tid >> 4;

    __shared__ __align__(16) float As[16][132];  // [k][m], stride 132: 16B-aligned rows
    __shared__ __align__(16) float Bs[16][132];  // [k][n]

    float acc[8][8];
    #pragma unroll
    for (int i = 0; i < 8; i++)
        #pragma unroll
        for (int j = 0; j < 8; j++) acc[i][j] = 0.f;

    for (int k0 = 0; k0 < D_; k0 += 16) {
        #pragma unroll
        for (int h2 = 0; h2 < 2; h2++) {          // A tile: 128 rows x 16 k (transposed)
            int lin = tid + h2 * 256;
            int row = lin >> 2;
            int kq  = (lin & 3) * 4;
            float4 v = *(const float4*)&X[(long)(m0 + row) * D_ + k0 + kq];
            As[kq + 0][row] = v.x;
            As[kq + 1][row] = v.y;
            As[kq + 2][row] = v.z;
            As[kq + 3][row] = v.w;
        }
        #pragma unroll
        for (int h2 = 0; h2 < 2; h2++) {          // B tile: 16 k x 128 n
            int f  = tid + h2 * 256;
            int kk = f >> 5;
            int nq = (f & 31) * 4;
            *(float4*)&Bs[kk][nq] = *(const float4*)&W[(long)(k0 + kk) * D_ + n0 + nq];
        }
        __syncthreads();
        #pragma unroll
        for (int kk = 0; kk < 16; kk++) {
            float a[8], bb[8];
            *(float4*)&a[0]  = *(const float4*)&As[kk][ty * 4];
            *(float4*)&a[4]  = *(const float4*)&As[kk][ty * 4 + 64];
            *(float4*)&bb[0] = *(const float4*)&Bs[kk][tx * 4];
            *(float4*)&bb[4] = *(const float4*)&Bs[kk][tx * 4 + 64];
            #pragma unroll
            for (int i = 0; i < 8; i++)
                #pragma unroll
                for (int j = 0; j < 8; j++)
                    acc[i][j] = fmaf(a[i], bb[j], acc[i][j]);
        }
        __syncthreads();
    }

    #pragma unroll
    for (int i = 0; i < 8; i++) {
        int m = m0 + ty * 4 + (i & 3) + (i >> 2) * 64;
        int b = m >> 11;           // m / S_
        int s = m & (S_ - 1);
        #pragma unroll
        for (int jh = 0; jh < 2; jh++) {
            int nbase = n0 + tx * 4 + jh * 64;
            int h = nbase >> 6;
            int d = nbase & 63;
            float4 vv;
            vv.x = (acc[i][jh * 4 + 0] + bias[nbase + 0]) * scale;
            vv.y = (acc[i][jh * 4 + 1] + bias[nbase + 1]) * scale;
            vv.z = (acc[i][jh * 4 + 2] + bias[nbase + 2]) * scale;
            vv.w = (acc[i][jh * 4 + 3] + bias[nbase + 3]) * scale;
            *(float4*)&out[(((long)b * H_ + h) * S_ + s) * 64 + d] = vv;
        }
    }
}

// ---------------------------------------------------------------------------
// Flash attention, fp32. One block per (b,h,q-tile of 32). 64-key tiles via
// LDS. Online softmax. Thread owns 2 q-rows x (4 k's strided by 16 | 4 d's).
//
// MASK SEMANTICS (critical): the reference adds BOTH mask terms in fp32:
//   scores = (raw + 1e9*(mk-1)) + 1e9*(mq-1)
// ulp(1e9) in fp32 is 64 and |raw| < ~8, so for a masked query row every
// unmasked key's score rounds to EXACTLY -1e9 (masked keys: -2e9). The
// reference softmax for masked query rows is therefore exactly uniform over
// unmasked keys — NOT softmax(raw). We replicate by doing the same fp32
// additions; the online softmax then naturally degenerates to the uniform
// average for those rows.
// ---------------------------------------------------------------------------
__global__ __launch_bounds__(256) void flash_attn(
    const float* __restrict__ Qg, const float* __restrict__ Kg,
    const float* __restrict__ Vg, const int* __restrict__ amask,
    float* __restrict__ ctx)
{
    const int bh = blockIdx.y;
    const int b  = bh >> 3;
    const int h  = bh & 7;
    const int q0 = blockIdx.x * QT;
    const int tid = threadIdx.x;
    const int qp   = tid >> 4;      // 0..15: pair of q rows (2qp, 2qp+1)
    const int kq16 = tid & 15;      // k-group base (scores) / d-group (PV)
    const int dq   = kq16 * 4;

    __shared__ __align__(16) float Qs[QT][68];   // pad 4: rows 16B-aligned, conflict-free
    __shared__ __align__(16) float Ks[KT][68];
    __shared__ __align__(16) float Vs[KT][68];
    __shared__ __align__(16) float Ps[QT][65];
    __shared__ float msk[KT];

    // load Q tile (32 x 64)
    #pragma unroll
    for (int h2 = 0; h2 < 2; h2++) {
        int lin = tid + h2 * 256;
        int row = lin >> 4;
        int c4  = (lin & 15) * 4;
        *(float4*)&Qs[row][c4] = *(const float4*)&Qg[((long)bh * S_ + q0 + row) * 64 + c4];
    }

    // per-query-row mask term (fp32-quantizing, see header comment)
    float mq[2];
    mq[0] = amask[b * S_ + q0 + qp * 2 + 0] ? 0.f : -1e9f;
    mq[1] = amask[b * S_ + q0 + qp * 2 + 1] ? 0.f : -1e9f;

    float O[2][4];
    #pragma unroll
    for (int i = 0; i < 2; i++)
        #pragma unroll
        for (int j = 0; j < 4; j++) O[i][j] = 0.f;
    float m_i[2] = {-1e30f, -1e30f};
    float l_i[2] = {0.f, 0.f};

    for (int k0 = 0; k0 < S_; k0 += KT) {
        __syncthreads();   // prev PV reads of Ks/Vs/Ps done
        #pragma unroll
        for (int h2 = 0; h2 < 4; h2++) {
            int lin = tid + h2 * 256;
            int row = lin >> 4;
            int c4  = (lin & 15) * 4;
            long g = ((long)bh * S_ + k0 + row) * 64 + c4;
            *(float4*)&Ks[row][c4] = *(const float4*)&Kg[g];
            *(float4*)&Vs[row][c4] = *(const float4*)&Vg[g];
        }
        if (tid < KT) msk[tid] = amask[b * S_ + k0 + tid] ? 0.f : -1e9f;
        __syncthreads();

        // scores: s[i][kk] for q rows 2qp+i, keys kq16 + 16*kk (strided => no bank conflict)
        float s[2][4];
        #pragma unroll
        for (int i = 0; i < 2; i++)
            #pragma unroll
            for (int kk = 0; kk < 4; kk++) s[i][kk] = 0.f;
        #pragma unroll 4
        for (int dd = 0; dd < 64; dd += 4) {
            float4 q0v = *(const float4*)&Qs[qp * 2][dd];
            float4 q1v = *(const float4*)&Qs[qp * 2 + 1][dd];
            #pragma unroll
            for (int kk = 0; kk < 4; kk++) {
                float4 kv = *(const float4*)&Ks[kq16 + kk * 16][dd];
                s[0][kk] += q0v.x * kv.x + q0v.y * kv.y + q0v.z * kv.z + q0v.w * kv.w;
                s[1][kk] += q1v.x * kv.x + q1v.y * kv.y + q1v.z * kv.z + q1v.w * kv.w;
            }
        }

        #pragma unroll
        for (int i = 0; i < 2; i++) {
            float mloc = -1e30f;
            #pragma unroll
            for (int kk = 0; kk < 4; kk++) {
                // reference order: (raw + key_term) + query_term, all fp32
                float sv = s[i][kk] + msk[kq16 + kk * 16];
                sv = sv + mq[i];
                s[i][kk] = sv;
                mloc = fmaxf(mloc, sv);
            }
            #pragma unroll
            for (int off = 1; off < 16; off <<= 1)
                mloc = fmaxf(mloc, __shfl_xor(mloc, off, 64));
            float m_new = fmaxf(m_i[i], mloc);
            float alpha = __expf(m_i[i] - m_new);
            float psum = 0.f;
            #pragma unroll
            for (int kk = 0; kk < 4; kk++) {
                float p = __expf(s[i][kk] - m_new);
                Ps[qp * 2 + i][kq16 + kk * 16] = p;
                psum += p;
            }
            #pragma unroll
            for (int off = 1; off < 16; off <<= 1)
                psum += __shfl_xor(psum, off, 64);
            l_i[i] = l_i[i] * alpha + psum;
            m_i[i] = m_new;
            #pragma unroll
            for (int j = 0; j < 4; j++) O[i][j] *= alpha;
        }
        __syncthreads();   // Ps visible

        #pragma unroll 2
        for (int kk = 0; kk < KT; kk++) {
            float4 vv = *(const float4*)&Vs[kk][dq];
            float p0 = Ps[qp * 2][kk];
            float p1 = Ps[qp * 2 + 1][kk];
            O[0][0] = fmaf(p0, vv.x, O[0][0]);
            O[0][1] = fmaf(p0, vv.y, O[0][1]);
            O[0][2] = fmaf(p0, vv.z, O[0][2]);
            O[0][3] = fmaf(p0, vv.w, O[0][3]);
            O[1][0] = fmaf(p1, vv.x, O[1][0]);
            O[1][1] = fmaf(p1, vv.y, O[1][1]);
            O[1][2] = fmaf(p1, vv.z, O[1][2]);
            O[1][3] = fmaf(p1, vv.w, O[1][3]);
        }
    }

    #pragma unroll
    for (int i = 0; i < 2; i++) {
        float inv = 1.f / l_i[i];
        int srow = q0 + qp * 2 + i;
        float4 vv;
        vv.x = O[i][0] * inv;
        vv.y = O[i][1] * inv;
        vv.z = O[i][2] * inv;
        vv.w = O[i][3] * inv;
        *(float4*)&ctx[((long)b * S_ + srow) * D_ + h * 64 + dq] = vv;
    }
}

// ---------------------------------------------------------------------------
// Output projection: out = ctx(8192x512) @ Wo(512x512) + bo, fp32 row-major.
// ---------------------------------------------------------------------------
__global__ __launch_bounds__(256) void proj_out(
    const float* __restrict__ Xc, const float* __restrict__ Wo,
    const float* __restrict__ bo, float* __restrict__ out)
{
    const int n0 = blockIdx.x * 128;
    const int m0 = blockIdx.y * 128;
    const int tid = threadIdx.x;
    const int tx = tid & 15;
    const int ty = tid >> 4;

    __shared__ __align__(16) float As[16][132];
    __shared__ __align__(16) float Bs[16][132];

    float acc[8][8];
    #pragma unroll
    for (int i = 0; i < 8; i++)
        #pragma unroll
        for (int j = 0; j < 8; j++) acc[i][j] = 0.f;

    for (int k0 = 0; k0 < D_; k0 += 16) {
        #pragma unroll
        for (int h2 = 0; h2 < 2; h2++) {
            int lin = tid + h2 * 256;
            int row = lin >> 2;
            int kq  = (lin & 3) * 4;
            float4 v = *(const float4*)&Xc[(long)(m0 + row) * D_ + k0 + kq];
            As[kq + 0][row] = v.x;
            As[kq + 1][row] = v.y;
            As[kq + 2][row] = v.z;
            As[kq + 3][row] = v.w;
        }
        #pragma unroll
        for (int h2 = 0; h2 < 2; h2++) {
            int f  = tid + h2 * 256;
            int kk = f >> 5;
            int nq = (f & 31) * 4;
            *(float4*)&Bs[kk][nq] = *(const float4*)&Wo[(long)(k0 + kk) * D_ + n0 + nq];
        }
        __syncthreads();
        #pragma unroll
        for (int kk = 0; kk < 16; kk++) {
            float a[8], bb[8];
            *(float4*)&a[0]  = *(const float4*)&As[kk][ty * 4];
            *(float4*)&a[4]  = *(const float4*)&As[kk][ty * 4 + 64];
            *(float4*)&bb[0] = *(const float4*)&Bs[kk][tx * 4];
            *(float4*)&bb[4] = *(const float4*)&Bs[kk][tx * 4 + 64];
            #pragma unroll
            for (int i = 0; i < 8; i++)
                #pragma unroll
                for (int j = 0; j < 8; j++)
                    acc[i][j] = fmaf(a[i], bb[j], acc[i][j]);
        }
        __syncthreads();
    }

    #pragma unroll
    for (int i = 0; i < 8; i++) {
        int m = m0 + ty * 4 + (i & 3) + (i >> 2) * 64;
        #pragma unroll
        for (int jh = 0; jh < 2; jh++) {
            int nbase = n0 + tx * 4 + jh * 64;
            float4 vv;
            vv.x = acc[i][jh * 4 + 0] + bo[nbase + 0];
            vv.y = acc[i][jh * 4 + 1] + bo[nbase + 1];
            vv.z = acc[i][jh * 4 + 2] + bo[nbase + 2];
            vv.w = acc[i][jh * 4 + 3] + bo[nbase + 3];
            *(float4*)&out[(long)m * D_ + nbase] = vv;
        }
    }
}

extern "C" void kernel_launch(void* const* d_in, const int* in_sizes, int n_in,
                              void* d_out, int out_size, void* d_ws, size_t ws_size,
                              hipStream_t stream)
{
    const float* query = (const float*)d_in[0];
    const float* value = (const float*)d_in[1];
    const int*   amask = (const int*)d_in[2];
    const float* Wq = (const float*)d_in[3];
    const float* bq = (const float*)d_in[4];
    const float* Wk = (const float*)d_in[5];
    const float* bk = (const float*)d_in[6];
    const float* Wv = (const float*)d_in[7];
    const float* bv = (const float*)d_in[8];
    const float* Wo = (const float*)d_in[9];
    const float* bo = (const float*)d_in[10];
    float* out = (float*)d_out;

    // workspace: Q,K,V (b,h,s,d) fp32 16 MiB each; ctx (b,s,h*dv) fp32 16 MiB
    char* ws = (char*)d_ws;
    float* Qb  = (float*)(ws);
    float* Kb  = (float*)(ws + ((size_t)16 << 20));
    float* Vb  = (float*)(ws + ((size_t)32 << 20));
    float* ctx = (float*)(ws + ((size_t)48 << 20));

    proj_qkv<<<dim3(4, 64, 3), 256, 0, stream>>>(query, value, Wq, bq, Wk, bk,
                                                 Wv, bv, Qb, Kb, Vb);
    flash_attn<<<dim3(S_ / QT, B_ * H_), 256, 0, stream>>>(Qb, Kb, Vb, amask, ctx);
    proj_out<<<dim3(4, 64), 256, 0, stream>>>(ctx, Wo, bo, out);
}

// Round 3
// 271.146 us; speedup vs baseline: 3.6822x; 3.6822x over previous
//
#include <hip/hip_runtime.h>

#define B_ 4
#define S_ 2048
#define D_ 512
#define H_ 8

typedef __attribute__((ext_vector_type(8))) __bf16 bf16x8;
typedef __attribute__((ext_vector_type(4))) float f32x4;

__device__ inline unsigned short f2b(float f) {
    union { float f; unsigned u; } v; v.f = f;
    unsigned r = v.u + 0x7FFFu + ((v.u >> 16) & 1u);   // RNE
    return (unsigned short)(r >> 16);
}

// ---------------------------------------------------------------------------
// Cast fp32 activations -> bf16 (row-major, unchanged layout).
// ---------------------------------------------------------------------------
__global__ __launch_bounds__(256) void cast_x(
    const float* __restrict__ q, const float* __restrict__ v,
    unsigned short* __restrict__ xq, unsigned short* __restrict__ xv)
{
    const float* src = blockIdx.z ? v : q;
    unsigned short* dst = blockIdx.z ? xv : xq;
    int i = (blockIdx.x * 256 + threadIdx.x) * 4;
    float4 f = *(const float4*)&src[i];
    ushort4 o;
    o.x = f2b(f.x); o.y = f2b(f.y); o.z = f2b(f.z); o.w = f2b(f.w);
    *(ushort4*)&dst[i] = o;
}

// ---------------------------------------------------------------------------
// Cast + transpose weights: Wt[n][k] = bf16(W[k][n]), 512x512.
// ---------------------------------------------------------------------------
__global__ __launch_bounds__(256) void cast_wt(
    const float* __restrict__ Wq, const float* __restrict__ Wk,
    const float* __restrict__ Wv, const float* __restrict__ Wo,
    unsigned short* __restrict__ Tq, unsigned short* __restrict__ Tk,
    unsigned short* __restrict__ Tv, unsigned short* __restrict__ To)
{
    int z = blockIdx.z;
    const float* W = (z == 0) ? Wq : (z == 1) ? Wk : (z == 2) ? Wv : Wo;
    unsigned short* T = (z == 0) ? Tq : (z == 1) ? Tk : (z == 2) ? Tv : To;
    int i = (blockIdx.x * 256 + threadIdx.x) * 4;   // output index, k fastest
    int n = i >> 9, k = i & 511;
    ushort4 o;
    o.x = f2b(W[(k + 0) * 512 + n]);
    o.y = f2b(W[(k + 1) * 512 + n]);
    o.z = f2b(W[(k + 2) * 512 + n]);
    o.w = f2b(W[(k + 3) * 512 + n]);
    *(ushort4*)&T[i] = o;
}

// ---------------------------------------------------------------------------
// bf16 MFMA GEMM 128x128 tile, 4 waves (2x2 of 64x64). X(8192x512)@W(512x512).
// which=0: Q -> (bh,s,d) bf16, scaled by 0.125. which=1: K -> (bh,s,d).
// which=2: V -> TRANSPOSED (bh,d,s) bf16 so flash reads are contiguous.
// ---------------------------------------------------------------------------
__global__ __launch_bounds__(256) void proj_qkv_mfma(
    const unsigned short* __restrict__ Xq, const unsigned short* __restrict__ Xv,
    const unsigned short* __restrict__ Wtq, const unsigned short* __restrict__ Wtk,
    const unsigned short* __restrict__ Wtv,
    const float* __restrict__ bq, const float* __restrict__ bk,
    const float* __restrict__ bv,
    unsigned short* __restrict__ Qb, unsigned short* __restrict__ Kb,
    unsigned short* __restrict__ VtG)
{
    const int which = blockIdx.z;
    const unsigned short* X  = (which == 0) ? Xq : Xv;
    const unsigned short* Wt = (which == 0) ? Wtq : (which == 1) ? Wtk : Wtv;
    const float* bias        = (which == 0) ? bq : (which == 1) ? bk : bv;
    const float scale        = (which == 0) ? 0.125f : 1.0f;

    const int m0 = blockIdx.y * 128, n0 = blockIdx.x * 128;
    const int tid = threadIdx.x;
    const int w = tid >> 6, lane = tid & 63;
    const int l15 = lane & 15, quad = lane >> 4;
    const int wm = (w >> 1) * 64, wn = (w & 1) * 64;

    __shared__ unsigned short As[128 * 72];   // [m][k], pad 8 -> 144B rows
    __shared__ unsigned short Bs[128 * 72];   // [n][k]

    f32x4 acc[4][4];
    #pragma unroll
    for (int i = 0; i < 4; i++)
        #pragma unroll
        for (int j = 0; j < 4; j++) acc[i][j] = (f32x4){0.f, 0.f, 0.f, 0.f};

    for (int k0 = 0; k0 < 512; k0 += 64) {
        __syncthreads();
        #pragma unroll
        for (int it = 0; it < 4; it++) {
            int ch = tid + it * 256;         // 1024 chunks of 8 bf16
            int row = ch >> 3, cg = (ch & 7) * 8;
            *(uint4*)&As[row * 72 + cg] = *(const uint4*)&X[(long)(m0 + row) * 512 + k0 + cg];
            *(uint4*)&Bs[row * 72 + cg] = *(const uint4*)&Wt[(long)(n0 + row) * 512 + k0 + cg];
        }
        __syncthreads();
        #pragma unroll
        for (int kc = 0; kc < 2; kc++) {
            bf16x8 a[4], bb[4];
            #pragma unroll
            for (int i = 0; i < 4; i++)
                a[i] = *(const bf16x8*)&As[(wm + 16 * i + l15) * 72 + kc * 32 + quad * 8];
            #pragma unroll
            for (int j = 0; j < 4; j++)
                bb[j] = *(const bf16x8*)&Bs[(wn + 16 * j + l15) * 72 + kc * 32 + quad * 8];
            #pragma unroll
            for (int i = 0; i < 4; i++)
                #pragma unroll
                for (int j = 0; j < 4; j++)
                    acc[i][j] = __builtin_amdgcn_mfma_f32_16x16x32_bf16(a[i], bb[j], acc[i][j], 0, 0, 0);
        }
    }

    #pragma unroll
    for (int j = 0; j < 4; j++) {
        int N = n0 + wn + 16 * j + l15;
        float bv_ = bias[N];
        int h = N >> 6, d = N & 63;
        #pragma unroll
        for (int i = 0; i < 4; i++) {
            int Mbase = m0 + wm + 16 * i + quad * 4;   // 4 consecutive s (same batch)
            int b = Mbase >> 11;
            int s = Mbase & 2047;
            if (which == 2) {
                ushort4 o;
                o.x = f2b(acc[i][j][0] + bv_);
                o.y = f2b(acc[i][j][1] + bv_);
                o.z = f2b(acc[i][j][2] + bv_);
                o.w = f2b(acc[i][j][3] + bv_);
                *(ushort4*)&VtG[(((long)b * H_ + h) * 64 + d) * 2048 + s] = o;
            } else {
                unsigned short* dst = (which == 0) ? Qb : Kb;
                #pragma unroll
                for (int r = 0; r < 4; r++)
                    dst[(((long)b * H_ + h) * 2048 + s + r) * 64 + d] =
                        f2b((acc[i][j][r] + bv_) * scale);
            }
        }
    }
}

// ---------------------------------------------------------------------------
// MFMA flash attention. Block = (b,h, 64-q tile), 4 waves x 16 q rows.
// K-tiles of 64. QK^T -> online softmax (C-layout regs) -> P via per-wave LDS
// (C->A layout transform) -> PV. Mask: fp32 (s + km) + mq, reproduces the
// reference's -1e9 quantization (masked q rows => exact uniform average).
// ---------------------------------------------------------------------------
__global__ __launch_bounds__(256) void flash_mfma(
    const unsigned short* __restrict__ Qg, const unsigned short* __restrict__ Kg,
    const unsigned short* __restrict__ VtG, const int* __restrict__ amask,
    unsigned short* __restrict__ ctxB)
{
    const int bh = blockIdx.y, b = bh >> 3, h = bh & 7;
    const int q0 = blockIdx.x * 64;
    const int tid = threadIdx.x;
    const int w = tid >> 6, lane = tid & 63;
    const int l15 = lane & 15, quad = lane >> 4;

    __shared__ unsigned short Ks[64 * 72];     // [key][d]
    __shared__ unsigned short Vt[64 * 72];     // [d][key]
    __shared__ unsigned short Ps[4 * 16 * 72]; // per-wave [q][key]
    __shared__ float kmsk[64];
    __shared__ float qmsk[64];

    if (tid < 64) qmsk[tid] = amask[b * S_ + q0 + tid] ? 0.f : -1e9f;

    bf16x8 qf[2];   // Q fragments resident in registers (direct from global)
    {
        const int qrow = q0 + w * 16 + l15;
        long base = ((long)bh * S_ + qrow) * 64 + quad * 8;
        qf[0] = *(const bf16x8*)&Qg[base];
        qf[1] = *(const bf16x8*)&Qg[base + 32];
    }
    __syncthreads();
    float mq[4];
    #pragma unroll
    for (int r = 0; r < 4; r++) mq[r] = qmsk[w * 16 + quad * 4 + r];

    f32x4 accO[4];
    #pragma unroll
    for (int dt = 0; dt < 4; dt++) accO[dt] = (f32x4){0.f, 0.f, 0.f, 0.f};
    float mi[4] = {-1e30f, -1e30f, -1e30f, -1e30f};
    float li[4] = {0.f, 0.f, 0.f, 0.f};
    unsigned short* pw = &Ps[w * 16 * 72];

    for (int k0 = 0; k0 < S_; k0 += 64) {
        __syncthreads();   // all waves done reading prev Ks/Vt
        #pragma unroll
        for (int it = 0; it < 2; it++) {
            int ch = tid + it * 256;        // 512 chunks of 8 bf16
            int row = ch >> 3, cg = (ch & 7) * 8;
            *(uint4*)&Ks[row * 72 + cg] = *(const uint4*)&Kg[((long)bh * S_ + k0 + row) * 64 + cg];
            *(uint4*)&Vt[row * 72 + cg] = *(const uint4*)&VtG[((long)bh * 64 + row) * 2048 + k0 + cg];
        }
        if (tid < 64) kmsk[tid] = amask[b * S_ + k0 + tid] ? 0.f : -1e9f;
        __syncthreads();

        // --- scores: 16q x 64k per wave ---
        f32x4 sc[4];
        #pragma unroll
        for (int nt = 0; nt < 4; nt++) {
            sc[nt] = (f32x4){0.f, 0.f, 0.f, 0.f};
            #pragma unroll
            for (int kc = 0; kc < 2; kc++) {
                bf16x8 kf = *(const bf16x8*)&Ks[(nt * 16 + l15) * 72 + kc * 32 + quad * 8];
                sc[nt] = __builtin_amdgcn_mfma_f32_16x16x32_bf16(qf[kc], kf, sc[nt], 0, 0, 0);
            }
        }
        float km[4];
        #pragma unroll
        for (int nt = 0; nt < 4; nt++) km[nt] = kmsk[nt * 16 + l15];

        // --- online softmax, rows r (q = quad*4+r), cols across 16 lanes ---
        #pragma unroll
        for (int r = 0; r < 4; r++) {
            float sv[4];
            float mloc = -1e30f;
            #pragma unroll
            for (int nt = 0; nt < 4; nt++) {
                float t = sc[nt][r] + km[nt];   // reference order:
                t = t + mq[r];                  // (raw + key) + query, fp32
                sv[nt] = t;
                mloc = fmaxf(mloc, t);
            }
            #pragma unroll
            for (int off = 1; off < 16; off <<= 1)
                mloc = fmaxf(mloc, __shfl_xor(mloc, off));
            float mn = fmaxf(mi[r], mloc);
            float alpha = __expf(mi[r] - mn);
            float ps = 0.f;
            #pragma unroll
            for (int nt = 0; nt < 4; nt++) {
                float p = __expf(sv[nt] - mn);
                pw[(quad * 4 + r) * 72 + nt * 16 + l15] = f2b(p);
                ps += p;
            }
            #pragma unroll
            for (int off = 1; off < 16; off <<= 1)
                ps += __shfl_xor(ps, off);
            li[r] = li[r] * alpha + ps;
            mi[r] = mn;
            #pragma unroll
            for (int dt = 0; dt < 4; dt++) accO[dt][r] *= alpha;
        }

        // --- PV: P (A-layout from per-wave LDS) x Vt (B-layout) ---
        bf16x8 pf[2];
        pf[0] = *(const bf16x8*)&pw[l15 * 72 + quad * 8];
        pf[1] = *(const bf16x8*)&pw[l15 * 72 + 32 + quad * 8];
        #pragma unroll
        for (int dt = 0; dt < 4; dt++) {
            #pragma unroll
            for (int kc = 0; kc < 2; kc++) {
                bf16x8 vf = *(const bf16x8*)&Vt[(dt * 16 + l15) * 72 + kc * 32 + quad * 8];
                accO[dt] = __builtin_amdgcn_mfma_f32_16x16x32_bf16(pf[kc], vf, accO[dt], 0, 0, 0);
            }
        }
    }

    float inv[4];
    #pragma unroll
    for (int r = 0; r < 4; r++) inv[r] = 1.f / li[r];
    #pragma unroll
    for (int dt = 0; dt < 4; dt++) {
        int d = h * 64 + dt * 16 + l15;
        #pragma unroll
        for (int r = 0; r < 4; r++) {
            int qrow = q0 + w * 16 + quad * 4 + r;
            ctxB[((long)(b * S_ + qrow)) * 512 + d] = f2b(accO[dt][r] * inv[r]);
        }
    }
}

// ---------------------------------------------------------------------------
// Output projection: out(fp32) = ctx_bf16 @ Wo + bo. Same MFMA GEMM body.
// ---------------------------------------------------------------------------
__global__ __launch_bounds__(256) void proj_out_mfma(
    const unsigned short* __restrict__ ctxB, const unsigned short* __restrict__ Wto,
    const float* __restrict__ bo, float* __restrict__ out)
{
    const int m0 = blockIdx.y * 128, n0 = blockIdx.x * 128;
    const int tid = threadIdx.x;
    const int w = tid >> 6, lane = tid & 63;
    const int l15 = lane & 15, quad = lane >> 4;
    const int wm = (w >> 1) * 64, wn = (w & 1) * 64;

    __shared__ unsigned short As[128 * 72];
    __shared__ unsigned short Bs[128 * 72];

    f32x4 acc[4][4];
    #pragma unroll
    for (int i = 0; i < 4; i++)
        #pragma unroll
        for (int j = 0; j < 4; j++) acc[i][j] = (f32x4){0.f, 0.f, 0.f, 0.f};

    for (int k0 = 0; k0 < 512; k0 += 64) {
        __syncthreads();
        #pragma unroll
        for (int it = 0; it < 4; it++) {
            int ch = tid + it * 256;
            int row = ch >> 3, cg = (ch & 7) * 8;
            *(uint4*)&As[row * 72 + cg] = *(const uint4*)&ctxB[(long)(m0 + row) * 512 + k0 + cg];
            *(uint4*)&Bs[row * 72 + cg] = *(const uint4*)&Wto[(long)(n0 + row) * 512 + k0 + cg];
        }
        __syncthreads();
        #pragma unroll
        for (int kc = 0; kc < 2; kc++) {
            bf16x8 a[4], bb[4];
            #pragma unroll
            for (int i = 0; i < 4; i++)
                a[i] = *(const bf16x8*)&As[(wm + 16 * i + l15) * 72 + kc * 32 + quad * 8];
            #pragma unroll
            for (int j = 0; j < 4; j++)
                bb[j] = *(const bf16x8*)&Bs[(wn + 16 * j + l15) * 72 + kc * 32 + quad * 8];
            #pragma unroll
            for (int i = 0; i < 4; i++)
                #pragma unroll
                for (int j = 0; j < 4; j++)
                    acc[i][j] = __builtin_amdgcn_mfma_f32_16x16x32_bf16(a[i], bb[j], acc[i][j], 0, 0, 0);
        }
    }

    #pragma unroll
    for (int j = 0; j < 4; j++) {
        int N = n0 + wn + 16 * j + l15;
        float bv_ = bo[N];
        #pragma unroll
        for (int i = 0; i < 4; i++) {
            int Mbase = m0 + wm + 16 * i + quad * 4;
            #pragma unroll
            for (int r = 0; r < 4; r++)
                out[(long)(Mbase + r) * 512 + N] = acc[i][j][r] + bv_;
        }
    }
}

extern "C" void kernel_launch(void* const* d_in, const int* in_sizes, int n_in,
                              void* d_out, int out_size, void* d_ws, size_t ws_size,
                              hipStream_t stream)
{
    const float* query = (const float*)d_in[0];
    const float* value = (const float*)d_in[1];
    const int*   amask = (const int*)d_in[2];
    const float* Wq = (const float*)d_in[3];
    const float* bq = (const float*)d_in[4];
    const float* Wk = (const float*)d_in[5];
    const float* bk = (const float*)d_in[6];
    const float* Wv = (const float*)d_in[7];
    const float* bv = (const float*)d_in[8];
    const float* Wo = (const float*)d_in[9];
    const float* bo = (const float*)d_in[10];
    float* out = (float*)d_out;

    char* ws = (char*)d_ws;
    const size_t MB = 1 << 20;
    unsigned short* Xq  = (unsigned short*)(ws);             // 8 MB
    unsigned short* Xv  = (unsigned short*)(ws + 8 * MB);    // 8 MB
    unsigned short* Wtq = (unsigned short*)(ws + 16 * MB);   // 0.5 MB each
    unsigned short* Wtk = (unsigned short*)(ws + 17 * MB);
    unsigned short* Wtv = (unsigned short*)(ws + 18 * MB);
    unsigned short* Wto = (unsigned short*)(ws + 19 * MB);
    unsigned short* Qb  = (unsigned short*)(ws + 20 * MB);   // 8 MB (bh,s,d)
    unsigned short* Kb  = (unsigned short*)(ws + 28 * MB);   // 8 MB (bh,s,d)
    unsigned short* VtG = (unsigned short*)(ws + 36 * MB);   // 8 MB (bh,d,s)
    unsigned short* ctx = (unsigned short*)(ws + 44 * MB);   // 8 MB (b*s, h*d)

    cast_x<<<dim3(4096, 1, 2), 256, 0, stream>>>(query, value, Xq, Xv);
    cast_wt<<<dim3(256, 1, 4), 256, 0, stream>>>(Wq, Wk, Wv, Wo, Wtq, Wtk, Wtv, Wto);
    proj_qkv_mfma<<<dim3(4, 64, 3), 256, 0, stream>>>(Xq, Xv, Wtq, Wtk, Wtv,
                                                      bq, bk, bv, Qb, Kb, VtG);
    flash_mfma<<<dim3(32, 32), 256, 0, stream>>>(Qb, Kb, VtG, amask, ctx);
    proj_out_mfma<<<dim3(4, 64), 256, 0, stream>>>(ctx, Wto, bo, out);
}

// Round 4
// 266.779 us; speedup vs baseline: 3.7424x; 1.0164x over previous
//
#include <hip/hip_runtime.h>

#define B_ 4
#define S_ 2048
#define D_ 512
#define H_ 8

typedef __attribute__((ext_vector_type(8))) __bf16 bf16x8;
typedef __attribute__((ext_vector_type(4))) float f32x4;

#define NEGBIG  -1.442695040e9f          // -1e9 * log2(e): masks live in exp2 domain
#define QSCALE  0.18033688011112042f     // 0.125 * log2(e) folded into Q

__device__ __forceinline__ unsigned short f2b(float f) {      // RNE
    union { float f; unsigned u; } v; v.f = f;
    unsigned r = v.u + 0x7FFFu + ((v.u >> 16) & 1u);
    return (unsigned short)(r >> 16);
}
// pack two floats -> two bf16 (round-nearest, ties-up): 2 adds + 1 v_perm
__device__ __forceinline__ unsigned pack_rn(float a, float b) {
    union { float f; unsigned u; } ua, ub; ua.f = a; ub.f = b;
    return __builtin_amdgcn_perm(ub.u + 0x8000u, ua.u + 0x8000u, 0x07060302u);
}

// ---------------------------------------------------------------------------
// Coalesced weight cast+transpose: Wt[n][k] = bf16(W[k][n]), via LDS tile.
// ---------------------------------------------------------------------------
__global__ __launch_bounds__(256) void cast_wt(
    const float* __restrict__ Wq, const float* __restrict__ Wk,
    const float* __restrict__ Wv, const float* __restrict__ Wo,
    unsigned short* __restrict__ Tq, unsigned short* __restrict__ Tk,
    unsigned short* __restrict__ Tv, unsigned short* __restrict__ To)
{
    int z = blockIdx.z;
    const float* W = (z == 0) ? Wq : (z == 1) ? Wk : (z == 2) ? Wv : Wo;
    unsigned short* T = (z == 0) ? Tq : (z == 1) ? Tk : (z == 2) ? Tv : To;
    int n0 = blockIdx.x * 64, k0 = blockIdx.y * 64;
    int tid = threadIdx.x;

    __shared__ float Ts[64][69];
    #pragma unroll
    for (int it = 0; it < 4; it++) {
        int lin = tid + it * 256;
        int kr = lin >> 4, c4 = (lin & 15) * 4;
        float4 v = *(const float4*)&W[(k0 + kr) * 512 + n0 + c4];
        Ts[kr][c4 + 0] = v.x; Ts[kr][c4 + 1] = v.y;
        Ts[kr][c4 + 2] = v.z; Ts[kr][c4 + 3] = v.w;
    }
    __syncthreads();
    int n = tid >> 2, kc = tid & 3;
    unsigned p[8];
    #pragma unroll
    for (int j = 0; j < 8; j++)
        p[j] = pack_rn(Ts[kc * 16 + 2 * j][n], Ts[kc * 16 + 2 * j + 1][n]);
    unsigned short* dst = &T[(n0 + n) * 512 + k0 + kc * 16];
    *(uint4*)dst       = *(uint4*)&p[0];
    *(uint4*)(dst + 8) = *(uint4*)&p[4];
}

// ---------------------------------------------------------------------------
// bf16 MFMA GEMM 128x128 tile. A staged directly from fp32 X (cast in-flight).
// which=0: Q -> (bh,s,d) scaled by 0.125*log2e. which=1: K -> (bh,s,d).
// which=2: V -> (bh,d,s) transposed.
// ---------------------------------------------------------------------------
__global__ __launch_bounds__(256) void proj_qkv_mfma(
    const float* __restrict__ Xq, const float* __restrict__ Xv,
    const unsigned short* __restrict__ Wtq, const unsigned short* __restrict__ Wtk,
    const unsigned short* __restrict__ Wtv,
    const float* __restrict__ bq, const float* __restrict__ bk,
    const float* __restrict__ bv,
    unsigned short* __restrict__ Qb, unsigned short* __restrict__ Kb,
    unsigned short* __restrict__ VtG)
{
    const int which = blockIdx.z;
    const float* X           = (which == 0) ? Xq : Xv;
    const unsigned short* Wt = (which == 0) ? Wtq : (which == 1) ? Wtk : Wtv;
    const float* bias        = (which == 0) ? bq : (which == 1) ? bk : bv;
    const float scale        = (which == 0) ? QSCALE : 1.0f;

    const int m0 = blockIdx.y * 128, n0 = blockIdx.x * 128;
    const int tid = threadIdx.x;
    const int w = tid >> 6, lane = tid & 63;
    const int l15 = lane & 15, quad = lane >> 4;
    const int wm = (w >> 1) * 64, wn = (w & 1) * 64;

    __shared__ unsigned short As[128 * 72];
    __shared__ unsigned short Bs[128 * 72];

    f32x4 acc[4][4];
    #pragma unroll
    for (int i = 0; i < 4; i++)
        #pragma unroll
        for (int j = 0; j < 4; j++) acc[i][j] = (f32x4){0.f, 0.f, 0.f, 0.f};

    for (int k0 = 0; k0 < 512; k0 += 64) {
        __syncthreads();
        #pragma unroll
        for (int it = 0; it < 8; it++) {          // A: fp32 -> bf16 in-flight
            int lin = tid + it * 256;
            int row = lin >> 4, c4 = (lin & 15) * 4;
            float4 v = *(const float4*)&X[(m0 + row) * 512 + k0 + c4];
            uint2 pp; pp.x = pack_rn(v.x, v.y); pp.y = pack_rn(v.z, v.w);
            *(uint2*)&As[row * 72 + c4] = pp;
        }
        #pragma unroll
        for (int it = 0; it < 4; it++) {          // B: precast bf16
            int ch = tid + it * 256;
            int row = ch >> 3, cg = (ch & 7) * 8;
            *(uint4*)&Bs[row * 72 + cg] = *(const uint4*)&Wt[(n0 + row) * 512 + k0 + cg];
        }
        __syncthreads();
        #pragma unroll
        for (int kc = 0; kc < 2; kc++) {
            bf16x8 a[4], bb[4];
            #pragma unroll
            for (int i = 0; i < 4; i++)
                a[i] = *(const bf16x8*)&As[(wm + 16 * i + l15) * 72 + kc * 32 + quad * 8];
            #pragma unroll
            for (int j = 0; j < 4; j++)
                bb[j] = *(const bf16x8*)&Bs[(wn + 16 * j + l15) * 72 + kc * 32 + quad * 8];
            #pragma unroll
            for (int i = 0; i < 4; i++)
                #pragma unroll
                for (int j = 0; j < 4; j++)
                    acc[i][j] = __builtin_amdgcn_mfma_f32_16x16x32_bf16(a[i], bb[j], acc[i][j], 0, 0, 0);
        }
    }

    #pragma unroll
    for (int j = 0; j < 4; j++) {
        int N = n0 + wn + 16 * j + l15;
        float bv_ = bias[N];
        int h = N >> 6, d = N & 63;
        #pragma unroll
        for (int i = 0; i < 4; i++) {
            int Mbase = m0 + wm + 16 * i + quad * 4;
            int b = Mbase >> 11, s = Mbase & 2047;
            if (which == 2) {
                ushort4 o;
                o.x = f2b(acc[i][j][0] + bv_);
                o.y = f2b(acc[i][j][1] + bv_);
                o.z = f2b(acc[i][j][2] + bv_);
                o.w = f2b(acc[i][j][3] + bv_);
                *(ushort4*)&VtG[(((b * H_ + h) * 64) + d) * 2048 + s] = o;
            } else {
                unsigned short* dst = (which == 0) ? Qb : Kb;
                #pragma unroll
                for (int r = 0; r < 4; r++)
                    dst[((b * H_ + h) * 2048 + s + r) * 64 + d] =
                        f2b((acc[i][j][r] + bv_) * scale);
            }
        }
    }
}

// ---------------------------------------------------------------------------
// Barrier-free MFMA flash attention. Block = (b,h, 128-q tile), 4 waves x 32q.
// S^T = K@Q^T (frags direct from global, K prefetched 1 tile ahead), masks
// folded into MFMA C-init (exact fp32-quantization reproduction), softmax in
// exp2 domain (log2e folded into Q), O^T = Vt@P^T with P via per-wave LDS.
// ---------------------------------------------------------------------------
__global__ __launch_bounds__(256) void flash_mfma(
    const unsigned short* __restrict__ Qg, const unsigned short* __restrict__ Kg,
    const unsigned short* __restrict__ VtG, const int* __restrict__ amask,
    unsigned short* __restrict__ ctxB)
{
    const int bh = blockIdx.y, b = bh >> 3, h = bh & 7;
    const int q0 = blockIdx.x * 128;
    const int tid = threadIdx.x;
    const int w = tid >> 6, lane = tid & 63;
    const int l15 = lane & 15, quad = lane >> 4;

    __shared__ unsigned short Ps[4 * 32 * 72];   // per-wave P^T->P region
    __shared__ float Km[4][64];                  // per-wave key-mask floats

    unsigned short* pw = &Ps[w * 32 * 72];
    float* kmB = Km[w];
    const int* amask_b = amask + b * 2048;

    // Q fragments (B-operand) + query mask, resident
    bf16x8 qf[2][2];
    float mq[2];
    const int qrow_base = q0 + w * 32;
    #pragma unroll
    for (int qb = 0; qb < 2; qb++) {
        int qrow = qrow_base + qb * 16 + l15;
        const unsigned short* p = &Qg[(bh * 2048 + qrow) * 64 + quad * 8];
        qf[qb][0] = *(const bf16x8*)p;
        qf[qb][1] = *(const bf16x8*)(p + 32);
        mq[qb] = amask_b[qrow] ? 0.f : NEGBIG;
    }

    const unsigned short* kbase = &Kg[(bh * 2048 + l15) * 64 + quad * 8];
    const unsigned short* vbase = &VtG[(bh * 64 + l15) * 2048 + quad * 8];

    // pipeline preamble: mask int + K frags for tile 0
    int mreg = amask_b[lane];
    bf16x8 kf[2][4][2];
    #pragma unroll
    for (int nt = 0; nt < 4; nt++)
        #pragma unroll
        for (int kc = 0; kc < 2; kc++)
            kf[0][nt][kc] = *(const bf16x8*)&kbase[nt * 16 * 64 + kc * 32];

    f32x4 accO[2][4];
    #pragma unroll
    for (int qb = 0; qb < 2; qb++)
        #pragma unroll
        for (int dt = 0; dt < 4; dt++) accO[qb][dt] = (f32x4){0.f, 0.f, 0.f, 0.f};
    float mi[2] = {-3.0e38f, -3.0e38f};
    float li[2] = {0.f, 0.f};

#define FLASH_TILE(KT, CUR, NXT)                                               \
    {                                                                          \
        const int ktn = ((KT) + 64 < S_) ? (KT) + 64 : (KT);                   \
        kmB[lane] = mreg ? 0.f : NEGBIG;        /* tile KT mask -> LDS */      \
        mreg = amask_b[ktn + lane];             /* prefetch next mask */       \
        bf16x8 vf[4][2];                                                       \
        _Pragma("unroll") for (int dt = 0; dt < 4; dt++)                       \
            _Pragma("unroll") for (int kc = 0; kc < 2; kc++)                   \
                vf[dt][kc] = *(const bf16x8*)&vbase[dt * 16 * 2048 + (KT) + kc * 32]; \
        _Pragma("unroll") for (int nt = 0; nt < 4; nt++)                       \
            _Pragma("unroll") for (int kc = 0; kc < 2; kc++)                   \
                kf[NXT][nt][kc] = *(const bf16x8*)&kbase[(ktn + nt * 16) * 64 + kc * 32]; \
        f32x4 kmf[4];                                                          \
        _Pragma("unroll") for (int nt = 0; nt < 4; nt++)                       \
            kmf[nt] = *(const f32x4*)&kmB[nt * 16 + quad * 4];                 \
        f32x4 sc[2][4];                                                        \
        _Pragma("unroll") for (int qb = 0; qb < 2; qb++)                       \
            _Pragma("unroll") for (int nt = 0; nt < 4; nt++) {                 \
                sc[qb][nt] = kmf[nt] + mq[qb];  /* masks as C-init: exact */   \
                _Pragma("unroll") for (int kc = 0; kc < 2; kc++)               \
                    sc[qb][nt] = __builtin_amdgcn_mfma_f32_16x16x32_bf16(      \
                        kf[CUR][nt][kc], qf[qb][kc], sc[qb][nt], 0, 0, 0);     \
            }                                                                  \
        _Pragma("unroll") for (int qb = 0; qb < 2; qb++) {                     \
            float mloc = sc[qb][0][0];                                         \
            _Pragma("unroll") for (int nt = 0; nt < 4; nt++)                   \
                _Pragma("unroll") for (int r = 0; r < 4; r++)                  \
                    mloc = fmaxf(mloc, sc[qb][nt][r]);                         \
            mloc = fmaxf(mloc, __shfl_xor(mloc, 16));                          \
            mloc = fmaxf(mloc, __shfl_xor(mloc, 32));                          \
            float mn = fmaxf(mi[qb], mloc);                                    \
            float alpha = __builtin_amdgcn_exp2f(mi[qb] - mn);                 \
            float ps = 0.f;                                                    \
            _Pragma("unroll") for (int nt = 0; nt < 4; nt++) {                 \
                float p0 = __builtin_amdgcn_exp2f(sc[qb][nt][0] - mn);         \
                float p1 = __builtin_amdgcn_exp2f(sc[qb][nt][1] - mn);         \
                float p2 = __builtin_amdgcn_exp2f(sc[qb][nt][2] - mn);         \
                float p3 = __builtin_amdgcn_exp2f(sc[qb][nt][3] - mn);         \
                ps += (p0 + p1) + (p2 + p3);                                   \
                int prow = (qb * 16 + l15) * 72 + nt * 16 + quad * 4;          \
                *(unsigned*)&pw[prow]     = pack_rn(p0, p1);                   \
                *(unsigned*)&pw[prow + 2] = pack_rn(p2, p3);                   \
            }                                                                  \
            ps += __shfl_xor(ps, 16);                                          \
            ps += __shfl_xor(ps, 32);                                          \
            li[qb] = li[qb] * alpha + ps;                                      \
            mi[qb] = mn;                                                       \
            _Pragma("unroll") for (int dt = 0; dt < 4; dt++) {                 \
                accO[qb][dt][0] *= alpha; accO[qb][dt][1] *= alpha;            \
                accO[qb][dt][2] *= alpha; accO[qb][dt][3] *= alpha;            \
            }                                                                  \
        }                                                                      \
        _Pragma("unroll") for (int qb = 0; qb < 2; qb++) {                     \
            bf16x8 pf0 = *(const bf16x8*)&pw[(qb * 16 + l15) * 72 + quad * 8]; \
            bf16x8 pf1 = *(const bf16x8*)&pw[(qb * 16 + l15) * 72 + 32 + quad * 8]; \
            _Pragma("unroll") for (int dt = 0; dt < 4; dt++) {                 \
                accO[qb][dt] = __builtin_amdgcn_mfma_f32_16x16x32_bf16(        \
                    vf[dt][0], pf0, accO[qb][dt], 0, 0, 0);                    \
                accO[qb][dt] = __builtin_amdgcn_mfma_f32_16x16x32_bf16(        \
                    vf[dt][1], pf1, accO[qb][dt], 0, 0, 0);                    \
            }                                                                  \
        }                                                                      \
    }

    for (int t = 0; t < 32; t += 2) {
        FLASH_TILE(t * 64, 0, 1);
        FLASH_TILE(t * 64 + 64, 1, 0);
    }
#undef FLASH_TILE

    #pragma unroll
    for (int qb = 0; qb < 2; qb++) {
        float inv = 1.f / li[qb];
        int q = qrow_base + qb * 16 + l15;
        int obase = (b * 2048 + q) * 512 + h * 64 + quad * 4;
        #pragma unroll
        for (int dt = 0; dt < 4; dt++) {
            ushort4 o;
            o.x = f2b(accO[qb][dt][0] * inv);
            o.y = f2b(accO[qb][dt][1] * inv);
            o.z = f2b(accO[qb][dt][2] * inv);
            o.w = f2b(accO[qb][dt][3] * inv);
            *(ushort4*)&ctxB[obase + dt * 16] = o;
        }
    }
}

// ---------------------------------------------------------------------------
// Output projection: out(fp32) = ctx_bf16 @ Wo + bo.
// ---------------------------------------------------------------------------
__global__ __launch_bounds__(256) void proj_out_mfma(
    const unsigned short* __restrict__ ctxB, const unsigned short* __restrict__ Wto,
    const float* __restrict__ bo, float* __restrict__ out)
{
    const int m0 = blockIdx.y * 128, n0 = blockIdx.x * 128;
    const int tid = threadIdx.x;
    const int w = tid >> 6, lane = tid & 63;
    const int l15 = lane & 15, quad = lane >> 4;
    const int wm = (w >> 1) * 64, wn = (w & 1) * 64;

    __shared__ unsigned short As[128 * 72];
    __shared__ unsigned short Bs[128 * 72];

    f32x4 acc[4][4];
    #pragma unroll
    for (int i = 0; i < 4; i++)
        #pragma unroll
        for (int j = 0; j < 4; j++) acc[i][j] = (f32x4){0.f, 0.f, 0.f, 0.f};

    for (int k0 = 0; k0 < 512; k0 += 64) {
        __syncthreads();
        #pragma unroll
        for (int it = 0; it < 4; it++) {
            int ch = tid + it * 256;
            int row = ch >> 3, cg = (ch & 7) * 8;
            *(uint4*)&As[row * 72 + cg] = *(const uint4*)&ctxB[(m0 + row) * 512 + k0 + cg];
            *(uint4*)&Bs[row * 72 + cg] = *(const uint4*)&Wto[(n0 + row) * 512 + k0 + cg];
        }
        __syncthreads();
        #pragma unroll
        for (int kc = 0; kc < 2; kc++) {
            bf16x8 a[4], bb[4];
            #pragma unroll
            for (int i = 0; i < 4; i++)
                a[i] = *(const bf16x8*)&As[(wm + 16 * i + l15) * 72 + kc * 32 + quad * 8];
            #pragma unroll
            for (int j = 0; j < 4; j++)
                bb[j] = *(const bf16x8*)&Bs[(wn + 16 * j + l15) * 72 + kc * 32 + quad * 8];
            #pragma unroll
            for (int i = 0; i < 4; i++)
                #pragma unroll
                for (int j = 0; j < 4; j++)
                    acc[i][j] = __builtin_amdgcn_mfma_f32_16x16x32_bf16(a[i], bb[j], acc[i][j], 0, 0, 0);
        }
    }

    #pragma unroll
    for (int j = 0; j < 4; j++) {
        int N = n0 + wn + 16 * j + l15;
        float bv_ = bo[N];
        #pragma unroll
        for (int i = 0; i < 4; i++) {
            int Mbase = m0 + wm + 16 * i + quad * 4;
            #pragma unroll
            for (int r = 0; r < 4; r++)
                out[(Mbase + r) * 512 + N] = acc[i][j][r] + bv_;
        }
    }
}

extern "C" void kernel_launch(void* const* d_in, const int* in_sizes, int n_in,
                              void* d_out, int out_size, void* d_ws, size_t ws_size,
                              hipStream_t stream)
{
    const float* query = (const float*)d_in[0];
    const float* value = (const float*)d_in[1];
    const int*   amask = (const int*)d_in[2];
    const float* Wq = (const float*)d_in[3];
    const float* bq = (const float*)d_in[4];
    const float* Wk = (const float*)d_in[5];
    const float* bk = (const float*)d_in[6];
    const float* Wv = (const float*)d_in[7];
    const float* bv = (const float*)d_in[8];
    const float* Wo = (const float*)d_in[9];
    const float* bo = (const float*)d_in[10];
    float* out = (float*)d_out;

    char* ws = (char*)d_ws;
    const size_t MB = 1 << 20;
    unsigned short* Wtq = (unsigned short*)(ws);
    unsigned short* Wtk = (unsigned short*)(ws + MB / 2);
    unsigned short* Wtv = (unsigned short*)(ws + MB);
    unsigned short* Wto = (unsigned short*)(ws + MB * 3 / 2);
    unsigned short* Qb  = (unsigned short*)(ws + 2 * MB);    // (bh,s,d)
    unsigned short* Kb  = (unsigned short*)(ws + 10 * MB);   // (bh,s,d)
    unsigned short* VtG = (unsigned short*)(ws + 18 * MB);   // (bh,d,s)
    unsigned short* ctx = (unsigned short*)(ws + 26 * MB);   // (b*s, h*d)

    cast_wt<<<dim3(8, 8, 4), 256, 0, stream>>>(Wq, Wk, Wv, Wo, Wtq, Wtk, Wtv, Wto);
    proj_qkv_mfma<<<dim3(4, 64, 3), 256, 0, stream>>>(query, value, Wtq, Wtk, Wtv,
                                                      bq, bk, bv, Qb, Kb, VtG);
    flash_mfma<<<dim3(16, 32), 256, 0, stream>>>(Qb, Kb, VtG, amask, ctx);
    proj_out_mfma<<<dim3(4, 64), 256, 0, stream>>>(ctx, Wto, bo, out);
}

// Round 5
// 214.788 us; speedup vs baseline: 4.6483x; 1.2421x over previous
//
#include <hip/hip_runtime.h>

#define B_ 4
#define S_ 2048
#define D_ 512
#define H_ 8

typedef __attribute__((ext_vector_type(8))) __bf16 bf16x8;
typedef __attribute__((ext_vector_type(4))) float f32x4;

#define NEGBIG  -1.442695040e9f          // -1e9 * log2(e): masks live in exp2 domain
#define QSCALE  0.18033688011112042f     // 0.125 * log2(e) folded into Q

// pack two floats -> two bf16 (RNE-ish, ties-up): 2 adds + 1 v_perm
__device__ __forceinline__ unsigned pack_rn(float a, float b) {
    union { float f; unsigned u; } ua, ub; ua.f = a; ub.f = b;
    return __builtin_amdgcn_perm(ub.u + 0x8000u, ua.u + 0x8000u, 0x07060302u);
}

// ---------------------------------------------------------------------------
// fp32 -> bf16 cast of activations (row-major unchanged).
// ---------------------------------------------------------------------------
__global__ __launch_bounds__(256) void cast_x(
    const float* __restrict__ q, const float* __restrict__ v,
    unsigned short* __restrict__ xq, unsigned short* __restrict__ xv)
{
    const float* src = blockIdx.z ? v : q;
    unsigned short* dst = blockIdx.z ? xv : xq;
    int i = (blockIdx.x * 256 + threadIdx.x) * 8;
    float4 f0 = *(const float4*)&src[i];
    float4 f1 = *(const float4*)&src[i + 4];
    uint4 o;
    o.x = pack_rn(f0.x, f0.y); o.y = pack_rn(f0.z, f0.w);
    o.z = pack_rn(f1.x, f1.y); o.w = pack_rn(f1.z, f1.w);
    *(uint4*)&dst[i] = o;
}

// ---------------------------------------------------------------------------
// Coalesced weight cast+transpose: Wt[n][k] = bf16(W[k][n]), via LDS tile.
// ---------------------------------------------------------------------------
__global__ __launch_bounds__(256) void cast_wt(
    const float* __restrict__ Wq, const float* __restrict__ Wk,
    const float* __restrict__ Wv, const float* __restrict__ Wo,
    unsigned short* __restrict__ Tq, unsigned short* __restrict__ Tk,
    unsigned short* __restrict__ Tv, unsigned short* __restrict__ To)
{
    int z = blockIdx.z;
    const float* W = (z == 0) ? Wq : (z == 1) ? Wk : (z == 2) ? Wv : Wo;
    unsigned short* T = (z == 0) ? Tq : (z == 1) ? Tk : (z == 2) ? Tv : To;
    int n0 = blockIdx.x * 64, k0 = blockIdx.y * 64;
    int tid = threadIdx.x;

    __shared__ float Ts[64][69];
    #pragma unroll
    for (int it = 0; it < 4; it++) {
        int lin = tid + it * 256;
        int kr = lin >> 4, c4 = (lin & 15) * 4;
        float4 v = *(const float4*)&W[(k0 + kr) * 512 + n0 + c4];
        Ts[kr][c4 + 0] = v.x; Ts[kr][c4 + 1] = v.y;
        Ts[kr][c4 + 2] = v.z; Ts[kr][c4 + 3] = v.w;
    }
    __syncthreads();
    int n = tid >> 2, kc = tid & 3;
    unsigned p[8];
    #pragma unroll
    for (int j = 0; j < 8; j++)
        p[j] = pack_rn(Ts[kc * 16 + 2 * j][n], Ts[kc * 16 + 2 * j + 1][n]);
    unsigned short* dst = &T[(n0 + n) * 512 + k0 + kc * 16];
    *(uint4*)dst       = *(uint4*)&p[0];
    *(uint4*)(dst + 8) = *(uint4*)&p[4];
}

// ---------------------------------------------------------------------------
// QKV projection GEMM, all-bf16 staging, 128x128 tile, 4 waves (2x2 of 64).
// acc[m][n] = sum_k A[m][k]*B[n][k].
// z=0 (Q): A=Wtq (m=feature), B=Xq (n=s) -> thread owns 4 consecutive d for
//          one s -> ushort4 stores to (bh,s,d), scaled by 0.125*log2e.
// z=1 (K): same with Wtk/Xv -> (bh,s,d).
// z=2 (V): A=Xv (m=s), B=Wtv (n=feature) -> 4 consecutive s for one d ->
//          ushort4 stores to transposed (bh,d,s).
// ---------------------------------------------------------------------------
__global__ __launch_bounds__(256) void proj_qkv_mfma(
    const unsigned short* __restrict__ Xq, const unsigned short* __restrict__ Xv,
    const unsigned short* __restrict__ Wtq, const unsigned short* __restrict__ Wtk,
    const unsigned short* __restrict__ Wtv,
    const float* __restrict__ bq, const float* __restrict__ bk,
    const float* __restrict__ bv,
    unsigned short* __restrict__ Qb, unsigned short* __restrict__ Kb,
    unsigned short* __restrict__ VtG)
{
    const int z = blockIdx.z;
    const unsigned short* A  = (z == 0) ? Wtq : (z == 1) ? Wtk : Xv;
    const unsigned short* Bm = (z == 0) ? Xq  : (z == 1) ? Xv  : Wtv;
    const float* bias        = (z == 0) ? bq  : (z == 1) ? bk  : bv;
    const int m0 = (z < 2) ? blockIdx.y * 128 : blockIdx.x * 128;
    const int n0 = (z < 2) ? blockIdx.x * 128 : blockIdx.y * 128;

    const int tid = threadIdx.x;
    const int w = tid >> 6, lane = tid & 63;
    const int l15 = lane & 15, quad = lane >> 4;
    const int wm = (w >> 1) * 64, wn = (w & 1) * 64;

    __shared__ unsigned short As[128 * 72];
    __shared__ unsigned short Bs[128 * 72];

    f32x4 acc[4][4];
    #pragma unroll
    for (int i = 0; i < 4; i++)
        #pragma unroll
        for (int j = 0; j < 4; j++) acc[i][j] = (f32x4){0.f, 0.f, 0.f, 0.f};

    for (int k0 = 0; k0 < 512; k0 += 64) {
        __syncthreads();
        #pragma unroll
        for (int it = 0; it < 2; it++) {
            int lin = tid + it * 256;
            int row = lin >> 2, c2 = (lin & 3) * 2;   // 2 of 8 chunks per row
            *(uint4*)&As[row * 72 + c2 * 8]     = *(const uint4*)&A[(m0 + row) * 512 + k0 + c2 * 8];
            *(uint4*)&As[row * 72 + c2 * 8 + 8] = *(const uint4*)&A[(m0 + row) * 512 + k0 + c2 * 8 + 8];
            *(uint4*)&Bs[row * 72 + c2 * 8]     = *(const uint4*)&Bm[(n0 + row) * 512 + k0 + c2 * 8];
            *(uint4*)&Bs[row * 72 + c2 * 8 + 8] = *(const uint4*)&Bm[(n0 + row) * 512 + k0 + c2 * 8 + 8];
        }
        __syncthreads();
        #pragma unroll
        for (int kc = 0; kc < 2; kc++) {
            bf16x8 a[4], bb[4];
            #pragma unroll
            for (int i = 0; i < 4; i++)
                a[i] = *(const bf16x8*)&As[(wm + 16 * i + l15) * 72 + kc * 32 + quad * 8];
            #pragma unroll
            for (int j = 0; j < 4; j++)
                bb[j] = *(const bf16x8*)&Bs[(wn + 16 * j + l15) * 72 + kc * 32 + quad * 8];
            #pragma unroll
            for (int i = 0; i < 4; i++)
                #pragma unroll
                for (int j = 0; j < 4; j++)
                    acc[i][j] = __builtin_amdgcn_mfma_f32_16x16x32_bf16(a[i], bb[j], acc[i][j], 0, 0, 0);
        }
    }

    if (z == 2) {
        // V: cols = feature, rows = s. ushort4 along s into (bh,d,s).
        #pragma unroll
        for (int j = 0; j < 4; j++) {
            int N = n0 + wn + 16 * j + l15;
            float bv_ = bias[N];
            int h = N >> 6, d = N & 63;
            #pragma unroll
            for (int i = 0; i < 4; i++) {
                int Mb = m0 + wm + 16 * i + quad * 4;
                int b = Mb >> 11, s = Mb & 2047;
                uint2 o;
                o.x = pack_rn(acc[i][j][0] + bv_, acc[i][j][1] + bv_);
                o.y = pack_rn(acc[i][j][2] + bv_, acc[i][j][3] + bv_);
                *(uint2*)&VtG[((b * H_ + h) * 64 + d) * 2048 + s] = o;
            }
        }
    } else {
        // Q/K: cols = s, rows = feature. ushort4 along d into (bh,s,d).
        unsigned short* dst = (z == 0) ? Qb : Kb;
        const float scale = (z == 0) ? QSCALE : 1.0f;
        #pragma unroll
        for (int j = 0; j < 4; j++) {
            int sg = n0 + wn + 16 * j + l15;
            int b = sg >> 11, s = sg & 2047;
            #pragma unroll
            for (int i = 0; i < 4; i++) {
                int F = m0 + wm + 16 * i + quad * 4;
                int h = F >> 6, d = F & 63;
                float4 b4 = *(const float4*)&bias[F];
                uint2 o;
                o.x = pack_rn((acc[i][j][0] + b4.x) * scale, (acc[i][j][1] + b4.y) * scale);
                o.y = pack_rn((acc[i][j][2] + b4.z) * scale, (acc[i][j][3] + b4.w) * scale);
                *(uint2*)&dst[((b * H_ + h) * 2048 + s) * 64 + d] = o;
            }
        }
    }
}

// ---------------------------------------------------------------------------
// MFMA flash attention. Block = (b,h, 128-q tile), 4 waves x 32q.
// K staged via double-buffered LDS (VGPR pipeline, ONE barrier per 64-key
// tile: load t+1 -> compute t from LDS -> ds_write t+1 -> barrier).
// V read direct from global (issued right after barrier, used ~600cyc later).
// Masks folded into MFMA C-init (exact fp32-quantization reproduction),
// softmax in exp2 domain (log2e folded into Q), P via per-wave LDS.
// ---------------------------------------------------------------------------
__global__ __launch_bounds__(256) void flash_mfma(
    const unsigned short* __restrict__ Qg, const unsigned short* __restrict__ Kg,
    const unsigned short* __restrict__ VtG, const int* __restrict__ amask,
    unsigned short* __restrict__ ctxB)
{
    const int bh = blockIdx.y, b = bh >> 3, h = bh & 7;
    const int q0 = blockIdx.x * 128;
    const int tid = threadIdx.x;
    const int w = tid >> 6, lane = tid & 63;
    const int l15 = lane & 15, quad = lane >> 4;

    __shared__ unsigned short Ks[2][64 * 72];    // double-buffered K tile [key][d]
    __shared__ unsigned short Ps[4][32 * 72];    // per-wave P region [q][key]
    __shared__ float Km[4][64];                  // per-wave key-mask floats

    const int* amask_b = amask + b * 2048;
    unsigned short* pw = &Ps[w][0];

    // Q fragments (B-operand) + query mask, resident
    bf16x8 qf[2][2];
    float mq[2];
    #pragma unroll
    for (int qb = 0; qb < 2; qb++) {
        int qrow = q0 + w * 32 + qb * 16 + l15;
        const unsigned short* p = &Qg[(bh * 2048 + qrow) * 64 + quad * 8];
        qf[qb][0] = *(const bf16x8*)p;
        qf[qb][1] = *(const bf16x8*)(p + 32);
        mq[qb] = amask_b[qrow] ? 0.f : NEGBIG;
    }

    // K staging: thread -> (row = tid>>2, chunks (tid&3)*2, +1) of 64x64 tile
    const int srow = tid >> 2;
    const int sch  = (tid & 3) * 2;
    const unsigned short* kgb = Kg + (long)bh * 2048 * 64;

    // preamble: stage tile 0 into Ks[0]
    {
        uint4 k0a = *(const uint4*)&kgb[srow * 64 + sch * 8];
        uint4 k0b = *(const uint4*)&kgb[srow * 64 + sch * 8 + 8];
        *(uint4*)&Ks[0][srow * 72 + sch * 8]     = k0a;
        *(uint4*)&Ks[0][srow * 72 + sch * 8 + 8] = k0b;
    }
    int mreg = amask_b[lane];

    f32x4 accO[2][4];
    #pragma unroll
    for (int qb = 0; qb < 2; qb++)
        #pragma unroll
        for (int dt = 0; dt < 4; dt++) accO[qb][dt] = (f32x4){0.f, 0.f, 0.f, 0.f};
    float mi[2] = {-3.0e38f, -3.0e38f};
    float li[2] = {0.f, 0.f};

    __syncthreads();

    for (int t = 0; t < 32; t++) {
        const int kt = t * 64;
        const int ktn = (t < 31) ? kt + 64 : kt;
        const int cur = t & 1, nxt = cur ^ 1;

        // [A] issue global loads: V frags for THIS tile, K staging for NEXT
        bf16x8 vf[4][2];
        #pragma unroll
        for (int dt = 0; dt < 4; dt++)
            #pragma unroll
            for (int kc = 0; kc < 2; kc++)
                vf[dt][kc] = *(const bf16x8*)&VtG[(bh * 64 + dt * 16 + l15) * 2048 + kt + kc * 32 + quad * 8];
        uint4 kst0 = *(const uint4*)&kgb[(ktn + srow) * 64 + sch * 8];
        uint4 kst1 = *(const uint4*)&kgb[(ktn + srow) * 64 + sch * 8 + 8];
        Km[w][lane] = mreg ? 0.f : NEGBIG;
        mreg = amask_b[ktn + lane];

        f32x4 kmf[4];
        #pragma unroll
        for (int nt = 0; nt < 4; nt++)
            kmf[nt] = *(const f32x4*)&Km[w][nt * 16 + quad * 4];

        // [C] QK from LDS buf[cur]: S^T (rows=key, cols=q)
        bf16x8 kf[4][2];
        #pragma unroll
        for (int nt = 0; nt < 4; nt++)
            #pragma unroll
            for (int kc = 0; kc < 2; kc++)
                kf[nt][kc] = *(const bf16x8*)&Ks[cur][(nt * 16 + l15) * 72 + kc * 32 + quad * 8];
        f32x4 sc[2][4];
        #pragma unroll
        for (int qb = 0; qb < 2; qb++)
            #pragma unroll
            for (int nt = 0; nt < 4; nt++) {
                sc[qb][nt] = kmf[nt] + mq[qb];   // masks as C-init: exact
                #pragma unroll
                for (int kc = 0; kc < 2; kc++)
                    sc[qb][nt] = __builtin_amdgcn_mfma_f32_16x16x32_bf16(
                        kf[nt][kc], qf[qb][kc], sc[qb][nt], 0, 0, 0);
            }

        // [D] online softmax (reduce over keys = in-lane + quad shfls)
        #pragma unroll
        for (int qb = 0; qb < 2; qb++) {
            float mloc = sc[qb][0][0];
            #pragma unroll
            for (int nt = 0; nt < 4; nt++)
                #pragma unroll
                for (int r = 0; r < 4; r++)
                    mloc = fmaxf(mloc, sc[qb][nt][r]);
            mloc = fmaxf(mloc, __shfl_xor(mloc, 16));
            mloc = fmaxf(mloc, __shfl_xor(mloc, 32));
            float mn = fmaxf(mi[qb], mloc);
            float alpha = __builtin_amdgcn_exp2f(mi[qb] - mn);
            float ps = 0.f;
            #pragma unroll
            for (int nt = 0; nt < 4; nt++) {
                float p0 = __builtin_amdgcn_exp2f(sc[qb][nt][0] - mn);
                float p1 = __builtin_amdgcn_exp2f(sc[qb][nt][1] - mn);
                float p2 = __builtin_amdgcn_exp2f(sc[qb][nt][2] - mn);
                float p3 = __builtin_amdgcn_exp2f(sc[qb][nt][3] - mn);
                ps += (p0 + p1) + (p2 + p3);
                int prow = (qb * 16 + l15) * 72 + nt * 16 + quad * 4;
                *(unsigned*)&pw[prow]     = pack_rn(p0, p1);
                *(unsigned*)&pw[prow + 2] = pack_rn(p2, p3);
            }
            ps += __shfl_xor(ps, 16);
            ps += __shfl_xor(ps, 32);
            li[qb] = li[qb] * alpha + ps;
            mi[qb] = mn;
            #pragma unroll
            for (int dt = 0; dt < 4; dt++) {
                accO[qb][dt][0] *= alpha; accO[qb][dt][1] *= alpha;
                accO[qb][dt][2] *= alpha; accO[qb][dt][3] *= alpha;
            }
        }

        // [E] PV: O^T += Vt (A) x P^T (B)
        #pragma unroll
        for (int qb = 0; qb < 2; qb++) {
            bf16x8 pf0 = *(const bf16x8*)&pw[(qb * 16 + l15) * 72 + quad * 8];
            bf16x8 pf1 = *(const bf16x8*)&pw[(qb * 16 + l15) * 72 + 32 + quad * 8];
            #pragma unroll
            for (int dt = 0; dt < 4; dt++) {
                accO[qb][dt] = __builtin_amdgcn_mfma_f32_16x16x32_bf16(
                    vf[dt][0], pf0, accO[qb][dt], 0, 0, 0);
                accO[qb][dt] = __builtin_amdgcn_mfma_f32_16x16x32_bf16(
                    vf[dt][1], pf1, accO[qb][dt], 0, 0, 0);
            }
        }

        // [F] commit next K tile to LDS (waits the [A] loads), [G] barrier
        *(uint4*)&Ks[nxt][srow * 72 + sch * 8]     = kst0;
        *(uint4*)&Ks[nxt][srow * 72 + sch * 8 + 8] = kst1;
        __syncthreads();
    }

    #pragma unroll
    for (int qb = 0; qb < 2; qb++) {
        float inv = 1.f / li[qb];
        int q = q0 + w * 32 + qb * 16 + l15;
        int obase = (b * 2048 + q) * 512 + h * 64 + quad * 4;
        #pragma unroll
        for (int dt = 0; dt < 4; dt++) {
            uint2 o;
            o.x = pack_rn(accO[qb][dt][0] * inv, accO[qb][dt][1] * inv);
            o.y = pack_rn(accO[qb][dt][2] * inv, accO[qb][dt][3] * inv);
            *(uint2*)&ctxB[obase + dt * 16] = o;
        }
    }
}

// ---------------------------------------------------------------------------
// Output projection: out(fp32) = ctx_bf16 @ Wo + bo.
// A=Wto (m=out-feature), B=ctx (n=s) -> epilogue is direct float4 stores.
// ---------------------------------------------------------------------------
__global__ __launch_bounds__(256) void proj_out_mfma(
    const unsigned short* __restrict__ ctxB, const unsigned short* __restrict__ Wto,
    const float* __restrict__ bo, float* __restrict__ out)
{
    const int m0 = blockIdx.y * 128, n0 = blockIdx.x * 128;
    const int tid = threadIdx.x;
    const int w = tid >> 6, lane = tid & 63;
    const int l15 = lane & 15, quad = lane >> 4;
    const int wm = (w >> 1) * 64, wn = (w & 1) * 64;

    __shared__ unsigned short As[128 * 72];
    __shared__ unsigned short Bs[128 * 72];

    f32x4 acc[4][4];
    #pragma unroll
    for (int i = 0; i < 4; i++)
        #pragma unroll
        for (int j = 0; j < 4; j++) acc[i][j] = (f32x4){0.f, 0.f, 0.f, 0.f};

    for (int k0 = 0; k0 < 512; k0 += 64) {
        __syncthreads();
        #pragma unroll
        for (int it = 0; it < 2; it++) {
            int lin = tid + it * 256;
            int row = lin >> 2, c2 = (lin & 3) * 2;
            *(uint4*)&As[row * 72 + c2 * 8]     = *(const uint4*)&Wto[(m0 + row) * 512 + k0 + c2 * 8];
            *(uint4*)&As[row * 72 + c2 * 8 + 8] = *(const uint4*)&Wto[(m0 + row) * 512 + k0 + c2 * 8 + 8];
            *(uint4*)&Bs[row * 72 + c2 * 8]     = *(const uint4*)&ctxB[(n0 + row) * 512 + k0 + c2 * 8];
            *(uint4*)&Bs[row * 72 + c2 * 8 + 8] = *(const uint4*)&ctxB[(n0 + row) * 512 + k0 + c2 * 8 + 8];
        }
        __syncthreads();
        #pragma unroll
        for (int kc = 0; kc < 2; kc++) {
            bf16x8 a[4], bb[4];
            #pragma unroll
            for (int i = 0; i < 4; i++)
                a[i] = *(const bf16x8*)&As[(wm + 16 * i + l15) * 72 + kc * 32 + quad * 8];
            #pragma unroll
            for (int j = 0; j < 4; j++)
                bb[j] = *(const bf16x8*)&Bs[(wn + 16 * j + l15) * 72 + kc * 32 + quad * 8];
            #pragma unroll
            for (int i = 0; i < 4; i++)
                #pragma unroll
                for (int j = 0; j < 4; j++)
                    acc[i][j] = __builtin_amdgcn_mfma_f32_16x16x32_bf16(a[i], bb[j], acc[i][j], 0, 0, 0);
        }
    }

    #pragma unroll
    for (int j = 0; j < 4; j++) {
        int sg = n0 + wn + 16 * j + l15;
        #pragma unroll
        for (int i = 0; i < 4; i++) {
            int F = m0 + wm + 16 * i + quad * 4;
            float4 b4 = *(const float4*)&bo[F];
            float4 vv;
            vv.x = acc[i][j][0] + b4.x;
            vv.y = acc[i][j][1] + b4.y;
            vv.z = acc[i][j][2] + b4.z;
            vv.w = acc[i][j][3] + b4.w;
            *(float4*)&out[sg * 512 + F] = vv;
        }
    }
}

extern "C" void kernel_launch(void* const* d_in, const int* in_sizes, int n_in,
                              void* d_out, int out_size, void* d_ws, size_t ws_size,
                              hipStream_t stream)
{
    const float* query = (const float*)d_in[0];
    const float* value = (const float*)d_in[1];
    const int*   amask = (const int*)d_in[2];
    const float* Wq = (const float*)d_in[3];
    const float* bq = (const float*)d_in[4];
    const float* Wk = (const float*)d_in[5];
    const float* bk = (const float*)d_in[6];
    const float* Wv = (const float*)d_in[7];
    const float* bv = (const float*)d_in[8];
    const float* Wo = (const float*)d_in[9];
    const float* bo = (const float*)d_in[10];
    float* out = (float*)d_out;

    char* ws = (char*)d_ws;
    const size_t MB = 1 << 20;
    unsigned short* Xbq = (unsigned short*)(ws);                  // 8 MB bf16
    unsigned short* Xbv = (unsigned short*)(ws + 8 * MB);         // 8 MB
    unsigned short* Wtq = (unsigned short*)(ws + 16 * MB);        // 0.5 MB each
    unsigned short* Wtk = (unsigned short*)(ws + 16 * MB + MB / 2);
    unsigned short* Wtv = (unsigned short*)(ws + 17 * MB);
    unsigned short* Wto = (unsigned short*)(ws + 17 * MB + MB / 2);
    unsigned short* Qb  = (unsigned short*)(ws + 18 * MB);        // 8 MB (bh,s,d)
    unsigned short* Kb  = (unsigned short*)(ws + 26 * MB);        // 8 MB (bh,s,d)
    unsigned short* VtG = (unsigned short*)(ws + 34 * MB);        // 8 MB (bh,d,s)
    unsigned short* ctx = (unsigned short*)(ws + 42 * MB);        // 8 MB (b*s, h*d)

    cast_x<<<dim3(2048, 1, 2), 256, 0, stream>>>(query, value, Xbq, Xbv);
    cast_wt<<<dim3(8, 8, 4), 256, 0, stream>>>(Wq, Wk, Wv, Wo, Wtq, Wtk, Wtv, Wto);
    proj_qkv_mfma<<<dim3(64, 4, 3), 256, 0, stream>>>(Xbq, Xbv, Wtq, Wtk, Wtv,
                                                      bq, bk, bv, Qb, Kb, VtG);
    flash_mfma<<<dim3(16, 32), 256, 0, stream>>>(Qb, Kb, VtG, amask, ctx);
    proj_out_mfma<<<dim3(64, 4), 256, 0, stream>>>(ctx, Wto, bo, out);
}